// Round 1
// baseline (754.036 us; speedup 1.0000x reference)
//
#include <hip/hip_runtime.h>

#define CDIV(a,b) (((a)+(b)-1)/(b))

// ---------------- preprocessing ----------------

__global__ __launch_bounds__(256) void k_init(float* deg, int* cnt, int n) {
    int i = blockIdx.x * 256 + threadIdx.x;
    if (i < n) { deg[i] = 2.0f; cnt[i] = 0; }   // self-loop weight 2.0 (improved=True)
}

__global__ __launch_bounds__(256) void k_count(const int* __restrict__ col,
                                               const float* __restrict__ ew,
                                               float* deg, int* cnt, int E) {
    int e = blockIdx.x * 256 + threadIdx.x;
    if (e < E) {
        int c = col[e];
        atomicAdd(&deg[c], ew[e]);
        atomicAdd(&cnt[c], 1);
    }
}

__global__ __launch_bounds__(256) void k_dis(float* deg, int n) {
    int i = blockIdx.x * 256 + threadIdx.x;
    if (i < n) {
        float d = deg[i];
        deg[i] = d > 0.f ? rsqrtf(d) : 0.f;   // deg >= 2 always, guard matches ref
    }
}

// exclusive prefix scan over cnt -> row_ptr (3-kernel hierarchical scan)
__global__ __launch_bounds__(256) void k_scan1(const int* __restrict__ cnt,
                                               int* __restrict__ row_ptr,
                                               int* __restrict__ bsum, int n) {
    int t = threadIdx.x;
    int base = blockIdx.x * 1024 + t * 4;
    int v0 = (base + 0 < n) ? cnt[base + 0] : 0;
    int v1 = (base + 1 < n) ? cnt[base + 1] : 0;
    int v2 = (base + 2 < n) ? cnt[base + 2] : 0;
    int v3 = (base + 3 < n) ? cnt[base + 3] : 0;
    int tsum = v0 + v1 + v2 + v3;
    int lane = t & 63, wv = t >> 6;
    int val = tsum;
    #pragma unroll
    for (int d = 1; d < 64; d <<= 1) {
        int u = __shfl_up(val, d, 64);
        if (lane >= d) val += u;
    }
    __shared__ int ws[4];
    if (lane == 63) ws[wv] = val;
    __syncthreads();
    int woff = 0;
    #pragma unroll
    for (int i = 0; i < 4; ++i) if (i < wv) woff += ws[i];
    int excl = woff + val - tsum;
    if (base + 0 < n) row_ptr[base + 0] = excl;  excl += v0;
    if (base + 1 < n) row_ptr[base + 1] = excl;  excl += v1;
    if (base + 2 < n) row_ptr[base + 2] = excl;  excl += v2;
    if (base + 3 < n) row_ptr[base + 3] = excl;
    if (t == 255) bsum[blockIdx.x] = woff + val;   // block total
}

__global__ __launch_bounds__(128) void k_scan2(int* bsum, int nb, int* row_ptr, int n, int E) {
    int t = threadIdx.x;
    int v = (t < nb) ? bsum[t] : 0;
    int lane = t & 63, wv = t >> 6;
    int val = v;
    #pragma unroll
    for (int d = 1; d < 64; d <<= 1) {
        int u = __shfl_up(val, d, 64);
        if (lane >= d) val += u;
    }
    __shared__ int ws[2];
    if (lane == 63) ws[wv] = val;
    __syncthreads();
    int woff = (wv == 1) ? ws[0] : 0;
    if (t < nb) bsum[t] = woff + val - v;   // exclusive
    if (t == 0) row_ptr[n] = E;             // total count is exactly E
}

__global__ __launch_bounds__(256) void k_scan3(int* __restrict__ row_ptr,
                                               const int* __restrict__ bsum,
                                               int* __restrict__ cursor, int n) {
    int i = blockIdx.x * 256 + threadIdx.x;
    if (i < n) {
        row_ptr[i] += bsum[i >> 10];
        cursor[i] = 0;
    }
}

__global__ __launch_bounds__(256) void k_fill(const int* __restrict__ rowi,
                                              const int* __restrict__ coli,
                                              const float* __restrict__ ew,
                                              const float* __restrict__ dis,
                                              const int* __restrict__ row_ptr,
                                              int* cursor,
                                              int* __restrict__ csr_row,
                                              float* __restrict__ csr_w, int E) {
    int e = blockIdx.x * 256 + threadIdx.x;
    if (e < E) {
        int c = coli[e], r = rowi[e];
        int pos = row_ptr[c] + atomicAdd(&cursor[c], 1);
        csr_row[pos] = r;
        csr_w[pos] = dis[r] * ew[e];        // norm = dis[r]*ew*dis[c]; dis[c] applied at segment end
    }
}

// ---------------- fp32 GEMM: C[n,128] = A[n,K] @ B[K,128] (+bias) ----------------
// 64 rows/block, 256 threads, each thread 8 rows x 4 cols.

__global__ __launch_bounds__(256) void k_gemm(const float* __restrict__ A,
                                              const float* __restrict__ B,
                                              const float* __restrict__ bias,
                                              float* __restrict__ C,
                                              int n, int K) {
    __shared__ float As[16][68];   // [k][row], padded to 68 (16B-aligned rows, conflict-free stage)
    __shared__ float Bs[16][128];  // [k][col]
    int t = threadIdx.x;
    int row0 = blockIdx.x * 64;
    int tx = t & 31;   // col group: cols tx*4..tx*4+3
    int ty = t >> 5;   // row group: rows ty*8..ty*8+7

    float acc[8][4];
    #pragma unroll
    for (int r = 0; r < 8; ++r)
        #pragma unroll
        for (int c = 0; c < 4; ++c) acc[r][c] = 0.f;

    int arow = t >> 2;
    int ak = (t & 3) * 4;
    int agr = row0 + arow; if (agr > n - 1) agr = n - 1;   // clamp (stores are guarded)
    const float* Arow = A + (size_t)agr * K + ak;

    int bk = t >> 5;
    int bj = (t & 31) * 4;

    for (int k0 = 0; k0 < K; k0 += 16) {
        float4 av = *(const float4*)(Arow + k0);
        As[ak + 0][arow] = av.x; As[ak + 1][arow] = av.y;
        As[ak + 2][arow] = av.z; As[ak + 3][arow] = av.w;
        *(float4*)&Bs[bk][bj]     = *(const float4*)(B + (size_t)(k0 + bk) * 128 + bj);
        *(float4*)&Bs[bk + 8][bj] = *(const float4*)(B + (size_t)(k0 + bk + 8) * 128 + bj);
        __syncthreads();
        #pragma unroll
        for (int kk = 0; kk < 16; ++kk) {
            float4 a0 = *(const float4*)&As[kk][ty * 8];
            float4 a1 = *(const float4*)&As[kk][ty * 8 + 4];
            float4 b  = *(const float4*)&Bs[kk][tx * 4];
            float ar[8] = {a0.x, a0.y, a0.z, a0.w, a1.x, a1.y, a1.z, a1.w};
            float br[4] = {b.x, b.y, b.z, b.w};
            #pragma unroll
            for (int r = 0; r < 8; ++r)
                #pragma unroll
                for (int c = 0; c < 4; ++c) acc[r][c] += ar[r] * br[c];
        }
        __syncthreads();
    }

    float4 bv = make_float4(0.f, 0.f, 0.f, 0.f);
    if (bias) bv = *(const float4*)(bias + tx * 4);
    #pragma unroll
    for (int r = 0; r < 8; ++r) {
        int gr = row0 + ty * 8 + r;
        if (gr < n) {
            float4 o;
            o.x = acc[r][0] + bv.x; o.y = acc[r][1] + bv.y;
            o.z = acc[r][2] + bv.z; o.w = acc[r][3] + bv.w;
            *(float4*)(C + (size_t)gr * 128 + tx * 4) = o;
        }
    }
}

// ---------------- aggregation: dst[c] = dis[c]*sum_e w_e*src[r_e] + 2*dis[c]^2*src[c] (+bias,relu) ----------------
// one wave (64 lanes) per node, float2 per lane = full 128-float row per edge, coalesced 512B.

__global__ __launch_bounds__(256) void k_agg(const float* __restrict__ src,
                                             const int* __restrict__ row_ptr,
                                             const int* __restrict__ csr_row,
                                             const float* __restrict__ csr_w,
                                             const float* __restrict__ dis,
                                             const float* __restrict__ bias,
                                             float* __restrict__ dst,
                                             int n, int do_relu) {
    int wid = (blockIdx.x * 256 + threadIdx.x) >> 6;
    int lane = threadIdx.x & 63;
    if (wid >= n) return;
    int e0 = row_ptr[wid], e1 = row_ptr[wid + 1];
    const float2* s2 = (const float2*)src;

    float ax = 0.f, ay = 0.f, bx = 0.f, by = 0.f;
    int e = e0;
    for (; e + 1 < e1; e += 2) {
        int   r0 = csr_row[e];     float w0 = csr_w[e];
        int   r1 = csr_row[e + 1]; float w1 = csr_w[e + 1];
        float2 v0 = s2[(size_t)r0 * 64 + lane];
        float2 v1 = s2[(size_t)r1 * 64 + lane];
        ax += w0 * v0.x; ay += w0 * v0.y;
        bx += w1 * v1.x; by += w1 * v1.y;
    }
    if (e < e1) {
        int r = csr_row[e]; float w = csr_w[e];
        float2 v = s2[(size_t)r * 64 + lane];
        ax += w * v.x; ay += w * v.y;
    }
    float dc = dis[wid];
    float2 sv = s2[(size_t)wid * 64 + lane];
    float sw = 2.f * dc * dc;
    float ox = dc * (ax + bx) + sw * sv.x;
    float oy = dc * (ay + by) + sw * sv.y;
    if (bias) { ox += bias[lane * 2]; oy += bias[lane * 2 + 1]; }
    if (do_relu) { ox = fmaxf(ox, 0.f); oy = fmaxf(oy, 0.f); }
    ((float2*)dst)[(size_t)wid * 64 + lane] = make_float2(ox, oy);
}

// ---------------- launch ----------------

extern "C" void kernel_launch(void* const* d_in, const int* in_sizes, int n_in,
                              void* d_out, int out_size, void* d_ws, size_t ws_size,
                              hipStream_t stream) {
    const float* x    = (const float*)d_in[0];
    const int*   ei   = (const int*)d_in[1];   // [2,E] flattened: row then col
    const float* ew   = (const float*)d_in[2];
    const float* W1   = (const float*)d_in[3];
    const float* b1   = (const float*)d_in[4];
    const float* Wmu  = (const float*)d_in[5];
    const float* bmu  = (const float*)d_in[6];
    const float* Wvar = (const float*)d_in[7];
    const float* bvar = (const float*)d_in[8];

    const int E = in_sizes[2];          // 1,600,000
    const int N = in_sizes[0] / 256;    // 100,000 (IN_DIM=256)
    const int* rowi = ei;
    const int* coli = ei + E;

    char* base = (char*)d_ws;
    size_t off = 0;
    auto alloc = [&](size_t bytes) -> void* {
        void* p = base + off;
        off = (off + bytes + 511) & ~(size_t)511;
        return p;
    };
    float* deg     = (float*)alloc((size_t)N * 4);       // becomes dis in place
    int*   cnt     = (int*)  alloc((size_t)N * 4);
    int*   row_ptr = (int*)  alloc((size_t)(N + 1) * 4);
    int*   cursor  = (int*)  alloc((size_t)N * 4);
    int*   bsum    = (int*)  alloc(1024 * 4);
    int*   csr_row = (int*)  alloc((size_t)E * 4);
    float* csr_w   = (float*)alloc((size_t)E * 4);
    float* xw      = (float*)alloc((size_t)N * 128 * 4);
    float* feat    = (float*)alloc((size_t)N * 128 * 4);
    float* g       = xw;   // xw dead after pass-1 aggregation

    float* mu  = (float*)d_out;
    float* var = mu + (size_t)N * 128;

    int nb = CDIV(N, 1024);

    k_init <<<CDIV(N, 256), 256, 0, stream>>>(deg, cnt, N);
    k_count<<<CDIV(E, 256), 256, 0, stream>>>(coli, ew, deg, cnt, E);
    k_dis  <<<CDIV(N, 256), 256, 0, stream>>>(deg, N);
    k_scan1<<<nb, 256, 0, stream>>>(cnt, row_ptr, bsum, N);
    k_scan2<<<1, 128, 0, stream>>>(bsum, nb, row_ptr, N, E);
    k_scan3<<<CDIV(N, 256), 256, 0, stream>>>(row_ptr, bsum, cursor, N);
    k_fill <<<CDIV(E, 256), 256, 0, stream>>>(rowi, coli, ew, deg, row_ptr, cursor, csr_row, csr_w, E);

    // layer 1: xw = x@W1 ; feat = relu(A·xw + b1)
    k_gemm<<<CDIV(N, 64), 256, 0, stream>>>(x, W1, nullptr, xw, N, 256);
    k_agg <<<CDIV(N * 64, 256), 256, 0, stream>>>(xw, row_ptr, csr_row, csr_w, deg, b1, feat, N, 1);

    // layer 2 (linearity swap): g = A·feat ; mu = g@Wmu+bmu ; var = g@Wvar+bvar
    k_agg <<<CDIV(N * 64, 256), 256, 0, stream>>>(feat, row_ptr, csr_row, csr_w, deg, nullptr, g, N, 0);
    k_gemm<<<CDIV(N, 64), 256, 0, stream>>>(g, Wmu,  bmu,  mu,  N, 128);
    k_gemm<<<CDIV(N, 64), 256, 0, stream>>>(g, Wvar, bvar, var, N, 128);
}

// Round 2
// 647.253 us; speedup vs baseline: 1.1650x; 1.1650x over previous
//
#include <hip/hip_runtime.h>
#include <hip/hip_bf16.h>

#define CDIV(a,b) (((a)+(b)-1)/(b))

typedef __attribute__((ext_vector_type(8))) short short8;   // 8 bf16 (4 VGPRs)
typedef __attribute__((ext_vector_type(4))) float f32x4;    // MFMA C/D frag

static __device__ inline short f2bf(float f) {
    union { __hip_bfloat16 h; short s; } u;
    u.h = __float2bfloat16(f);
    return u.s;
}

// ---------------- preprocessing ----------------

__global__ __launch_bounds__(256) void k_init(float* deg, int* cnt, int n) {
    int i = blockIdx.x * 256 + threadIdx.x;
    if (i < n) { deg[i] = 2.0f; cnt[i] = 0; }   // self-loop weight 2.0 (improved=True)
}

__global__ __launch_bounds__(256) void k_count(const int* __restrict__ col,
                                               const float* __restrict__ ew,
                                               float* deg, int* cnt, int E) {
    int e = blockIdx.x * 256 + threadIdx.x;
    if (e < E) {
        int c = col[e];
        atomicAdd(&deg[c], ew[e]);
        atomicAdd(&cnt[c], 1);
    }
}

__global__ __launch_bounds__(256) void k_dis(float* deg, int n) {
    int i = blockIdx.x * 256 + threadIdx.x;
    if (i < n) {
        float d = deg[i];
        deg[i] = d > 0.f ? rsqrtf(d) : 0.f;
    }
}

// exclusive prefix scan over cnt -> row_ptr (3-kernel hierarchical scan)
__global__ __launch_bounds__(256) void k_scan1(const int* __restrict__ cnt,
                                               int* __restrict__ row_ptr,
                                               int* __restrict__ bsum, int n) {
    int t = threadIdx.x;
    int base = blockIdx.x * 1024 + t * 4;
    int v0 = (base + 0 < n) ? cnt[base + 0] : 0;
    int v1 = (base + 1 < n) ? cnt[base + 1] : 0;
    int v2 = (base + 2 < n) ? cnt[base + 2] : 0;
    int v3 = (base + 3 < n) ? cnt[base + 3] : 0;
    int tsum = v0 + v1 + v2 + v3;
    int lane = t & 63, wv = t >> 6;
    int val = tsum;
    #pragma unroll
    for (int d = 1; d < 64; d <<= 1) {
        int u = __shfl_up(val, d, 64);
        if (lane >= d) val += u;
    }
    __shared__ int ws[4];
    if (lane == 63) ws[wv] = val;
    __syncthreads();
    int woff = 0;
    #pragma unroll
    for (int i = 0; i < 4; ++i) if (i < wv) woff += ws[i];
    int excl = woff + val - tsum;
    if (base + 0 < n) row_ptr[base + 0] = excl;  excl += v0;
    if (base + 1 < n) row_ptr[base + 1] = excl;  excl += v1;
    if (base + 2 < n) row_ptr[base + 2] = excl;  excl += v2;
    if (base + 3 < n) row_ptr[base + 3] = excl;
    if (t == 255) bsum[blockIdx.x] = woff + val;   // block total
}

__global__ __launch_bounds__(128) void k_scan2(int* bsum, int nb, int* row_ptr, int n, int E) {
    int t = threadIdx.x;
    int v = (t < nb) ? bsum[t] : 0;
    int lane = t & 63, wv = t >> 6;
    int val = v;
    #pragma unroll
    for (int d = 1; d < 64; d <<= 1) {
        int u = __shfl_up(val, d, 64);
        if (lane >= d) val += u;
    }
    __shared__ int ws[2];
    if (lane == 63) ws[wv] = val;
    __syncthreads();
    int woff = (wv == 1) ? ws[0] : 0;
    if (t < nb) bsum[t] = woff + val - v;   // exclusive
    if (t == 0) row_ptr[n] = E;
}

__global__ __launch_bounds__(256) void k_scan3(int* __restrict__ row_ptr,
                                               const int* __restrict__ bsum,
                                               int* __restrict__ cursor, int n) {
    int i = blockIdx.x * 256 + threadIdx.x;
    if (i < n) {
        row_ptr[i] += bsum[i >> 10];
        cursor[i] = 0;
    }
}

__global__ __launch_bounds__(256) void k_fill(const int* __restrict__ rowi,
                                              const int* __restrict__ coli,
                                              const float* __restrict__ ew,
                                              const float* __restrict__ dis,
                                              const int* __restrict__ row_ptr,
                                              int* cursor,
                                              int* __restrict__ csr_row,
                                              float* __restrict__ csr_w, int E) {
    int e = blockIdx.x * 256 + threadIdx.x;
    if (e < E) {
        int c = coli[e], r = rowi[e];
        int pos = row_ptr[c] + atomicAdd(&cursor[c], 1);
        csr_row[pos] = r;
        csr_w[pos] = dis[r] * ew[e];        // dis[c] applied at segment end
    }
}

// ---------------- W prep: Wt[n][k] = bf16(W[k][n]) ----------------

__global__ __launch_bounds__(256) void k_prep_w(const float* __restrict__ W,
                                                short* __restrict__ Wt, int K) {
    int i = blockIdx.x * 256 + threadIdx.x;   // over 128*K
    if (i < 128 * K) {
        int k = i % K, ncol = i / K;
        Wt[i] = f2bf(W[(size_t)k * 128 + ncol]);
    }
}

// ---------------- bf16 MFMA GEMM: C[n,128] = A[n,K](fp32, cvt inline) @ B[K,128] ----------------
// B given pre-transposed bf16: Bt[128][K]. 512 threads = 8 waves, 256 rows/block,
// each wave: 32 rows (2 row-frags) x 128 cols (8 col-frags), mfma_f32_16x16x32_bf16.
// Bt staged in LDS with XOR swizzle (T2): kbyte ^= (col&7)<<4 kills the 512B-stride
// 16-way bank conflict on the b-frag ds_read_b128.

template<int K>
__global__ __launch_bounds__(512) void k_gemm_mfma(const float* __restrict__ A,
                                                   const short* __restrict__ Bt,
                                                   const float* __restrict__ bias,
                                                   float* __restrict__ C, int n) {
    __shared__ short Blds[128 * K];
    int t = threadIdx.x;

    // stage Bt -> LDS (swizzled), 16B chunks
    const int CHK = K / 8;                    // 16B chunks per row
    for (int c = t; c < 128 * CHK; c += 512) {
        int col = c / CHK;
        int kb  = (c % CHK) * 16;             // byte offset in row
        int dst = col * (K * 2) + (kb ^ ((col & 7) << 4));
        *(float4*)((char*)Blds + dst) =
            *(const float4*)((const char*)Bt + (size_t)col * (K * 2) + kb);
    }
    __syncthreads();

    int wave = t >> 6, lane = t & 63;
    int lg = lane >> 4, lr = lane & 15;       // lane group (k-group), lane row/col
    long row_base = (long)blockIdx.x * 256 + wave * 32;

    long ra0 = row_base + lr;      if (ra0 > n - 1) ra0 = n - 1;   // clamped, stores guarded
    long ra1 = row_base + 16 + lr; if (ra1 > n - 1) ra1 = n - 1;

    f32x4 acc[2][8];
    #pragma unroll
    for (int i = 0; i < 2; ++i)
        #pragma unroll
        for (int j = 0; j < 8; ++j) acc[i][j] = (f32x4){0.f, 0.f, 0.f, 0.f};

    const float* pa0 = A + ra0 * K + lg * 8;
    const float* pa1 = A + ra1 * K + lg * 8;

    for (int k0 = 0; k0 < K; k0 += 32) {
        // A frags: 8 fp32 -> 8 bf16 per row-frag
        float4 x0 = *(const float4*)(pa0 + k0);
        float4 x1 = *(const float4*)(pa0 + k0 + 4);
        float4 y0 = *(const float4*)(pa1 + k0);
        float4 y1 = *(const float4*)(pa1 + k0 + 4);
        short8 a0, a1;
        a0[0]=f2bf(x0.x); a0[1]=f2bf(x0.y); a0[2]=f2bf(x0.z); a0[3]=f2bf(x0.w);
        a0[4]=f2bf(x1.x); a0[5]=f2bf(x1.y); a0[6]=f2bf(x1.z); a0[7]=f2bf(x1.w);
        a1[0]=f2bf(y0.x); a1[1]=f2bf(y0.y); a1[2]=f2bf(y0.z); a1[3]=f2bf(y0.w);
        a1[4]=f2bf(y1.x); a1[5]=f2bf(y1.y); a1[6]=f2bf(y1.z); a1[7]=f2bf(y1.w);

        int kb = (k0 + lg * 8) * 2;           // this lane's k byte offset
        #pragma unroll
        for (int cb = 0; cb < 8; ++cb) {
            int col = cb * 16 + lr;
            short8 b = *(short8*)((char*)Blds + col * (K * 2) + (kb ^ ((col & 7) << 4)));
            acc[0][cb] = __builtin_amdgcn_mfma_f32_16x16x32_bf16(a0, b, acc[0][cb], 0, 0, 0);
            acc[1][cb] = __builtin_amdgcn_mfma_f32_16x16x32_bf16(a1, b, acc[1][cb], 0, 0, 0);
        }
    }

    // epilogue: D col = lane&15, row = (lane>>4)*4 + reg
    #pragma unroll
    for (int rf = 0; rf < 2; ++rf) {
        #pragma unroll
        for (int cb = 0; cb < 8; ++cb) {
            int col = cb * 16 + lr;
            float bv = bias ? bias[col] : 0.f;
            #pragma unroll
            for (int r = 0; r < 4; ++r) {
                long row = row_base + rf * 16 + lg * 4 + r;
                if (row < n) C[row * 128 + col] = acc[rf][cb][r] + bv;
            }
        }
    }
}

// ---------------- aggregation (unchanged): dst[c] = dis[c]*sum w_e*src[r_e] + 2*dis[c]^2*src[c] ----------------

__global__ __launch_bounds__(256) void k_agg(const float* __restrict__ src,
                                             const int* __restrict__ row_ptr,
                                             const int* __restrict__ csr_row,
                                             const float* __restrict__ csr_w,
                                             const float* __restrict__ dis,
                                             const float* __restrict__ bias,
                                             float* __restrict__ dst,
                                             int n, int do_relu) {
    int wid = (blockIdx.x * 256 + threadIdx.x) >> 6;
    int lane = threadIdx.x & 63;
    if (wid >= n) return;
    int e0 = row_ptr[wid], e1 = row_ptr[wid + 1];
    const float2* s2 = (const float2*)src;

    float ax = 0.f, ay = 0.f, bx = 0.f, by = 0.f;
    int e = e0;
    for (; e + 1 < e1; e += 2) {
        int   r0 = csr_row[e];     float w0 = csr_w[e];
        int   r1 = csr_row[e + 1]; float w1 = csr_w[e + 1];
        float2 v0 = s2[(size_t)r0 * 64 + lane];
        float2 v1 = s2[(size_t)r1 * 64 + lane];
        ax += w0 * v0.x; ay += w0 * v0.y;
        bx += w1 * v1.x; by += w1 * v1.y;
    }
    if (e < e1) {
        int r = csr_row[e]; float w = csr_w[e];
        float2 v = s2[(size_t)r * 64 + lane];
        ax += w * v.x; ay += w * v.y;
    }
    float dc = dis[wid];
    float2 sv = s2[(size_t)wid * 64 + lane];
    float sw = 2.f * dc * dc;
    float ox = dc * (ax + bx) + sw * sv.x;
    float oy = dc * (ay + by) + sw * sv.y;
    if (bias) { ox += bias[lane * 2]; oy += bias[lane * 2 + 1]; }
    if (do_relu) { ox = fmaxf(ox, 0.f); oy = fmaxf(oy, 0.f); }
    ((float2*)dst)[(size_t)wid * 64 + lane] = make_float2(ox, oy);
}

// ---------------- launch ----------------

extern "C" void kernel_launch(void* const* d_in, const int* in_sizes, int n_in,
                              void* d_out, int out_size, void* d_ws, size_t ws_size,
                              hipStream_t stream) {
    const float* x    = (const float*)d_in[0];
    const int*   ei   = (const int*)d_in[1];   // [2,E]: row then col
    const float* ew   = (const float*)d_in[2];
    const float* W1   = (const float*)d_in[3];
    const float* b1   = (const float*)d_in[4];
    const float* Wmu  = (const float*)d_in[5];
    const float* bmu  = (const float*)d_in[6];
    const float* Wvar = (const float*)d_in[7];
    const float* bvar = (const float*)d_in[8];

    const int E = in_sizes[2];          // 1,600,000
    const int N = in_sizes[0] / 256;    // 100,000
    const int* rowi = ei;
    const int* coli = ei + E;

    char* base = (char*)d_ws;
    size_t off = 0;
    auto alloc = [&](size_t bytes) -> void* {
        void* p = base + off;
        off = (off + bytes + 511) & ~(size_t)511;
        return p;
    };
    float* deg     = (float*)alloc((size_t)N * 4);       // becomes dis in place
    int*   cnt     = (int*)  alloc((size_t)N * 4);
    int*   row_ptr = (int*)  alloc((size_t)(N + 1) * 4);
    int*   cursor  = (int*)  alloc((size_t)N * 4);
    int*   bsum    = (int*)  alloc(1024 * 4);
    int*   csr_row = (int*)  alloc((size_t)E * 4);
    float* csr_w   = (float*)alloc((size_t)E * 4);
    float* xw      = (float*)alloc((size_t)N * 128 * 4);
    float* feat    = (float*)alloc((size_t)N * 128 * 4);
    short* W1t     = (short*)alloc((size_t)256 * 128 * 2);
    short* Wmut    = (short*)alloc((size_t)128 * 128 * 2);
    short* Wvart   = (short*)alloc((size_t)128 * 128 * 2);
    float* g       = xw;   // xw dead after pass-1 aggregation

    float* mu  = (float*)d_out;
    float* var = mu + (size_t)N * 128;

    int nb = CDIV(N, 1024);

    k_init  <<<CDIV(N, 256), 256, 0, stream>>>(deg, cnt, N);
    k_count <<<CDIV(E, 256), 256, 0, stream>>>(coli, ew, deg, cnt, E);
    k_dis   <<<CDIV(N, 256), 256, 0, stream>>>(deg, N);
    k_scan1 <<<nb, 256, 0, stream>>>(cnt, row_ptr, bsum, N);
    k_scan2 <<<1, 128, 0, stream>>>(bsum, nb, row_ptr, N, E);
    k_scan3 <<<CDIV(N, 256), 256, 0, stream>>>(row_ptr, bsum, cursor, N);
    k_fill  <<<CDIV(E, 256), 256, 0, stream>>>(rowi, coli, ew, deg, row_ptr, cursor, csr_row, csr_w, E);
    k_prep_w<<<CDIV(256 * 128, 256), 256, 0, stream>>>(W1,   W1t,   256);
    k_prep_w<<<CDIV(128 * 128, 256), 256, 0, stream>>>(Wmu,  Wmut,  128);
    k_prep_w<<<CDIV(128 * 128, 256), 256, 0, stream>>>(Wvar, Wvart, 128);

    // layer 1: xw = x@W1 ; feat = relu(A·xw + b1)
    k_gemm_mfma<256><<<CDIV(N, 256), 512, 0, stream>>>(x, W1t, nullptr, xw, N);
    k_agg<<<CDIV(N * 64, 256), 256, 0, stream>>>(xw, row_ptr, csr_row, csr_w, deg, b1, feat, N, 1);

    // layer 2 (linearity swap): g = A·feat ; mu = g@Wmu+bmu ; var = g@Wvar+bvar
    k_agg<<<CDIV(N * 64, 256), 256, 0, stream>>>(feat, row_ptr, csr_row, csr_w, deg, nullptr, g, N, 0);
    k_gemm_mfma<128><<<CDIV(N, 256), 512, 0, stream>>>(g, Wmut,  bmu,  mu,  N);
    k_gemm_mfma<128><<<CDIV(N, 256), 512, 0, stream>>>(g, Wvart, bvar, var, N);
}

// Round 3
// 472.274 us; speedup vs baseline: 1.5966x; 1.3705x over previous
//
#include <hip/hip_runtime.h>
#include <hip/hip_bf16.h>

#define CDIV(a,b) (((a)+(b)-1)/(b))

typedef __attribute__((ext_vector_type(8))) short short8;   // 8 bf16 (4 VGPRs)
typedef __attribute__((ext_vector_type(4))) float f32x4;    // MFMA C/D frag

static __device__ inline short f2bf(float f) {
    union { __hip_bfloat16 h; short s; } u;
    u.h = __float2bfloat16(f);
    return u.s;
}
static __device__ inline ushort f2bfu(float f) { return (ushort)f2bf(f); }
static __device__ inline float bfu_lo(uint v) { return __uint_as_float(v << 16); }
static __device__ inline float bfu_hi(uint v) { return __uint_as_float(v & 0xffff0000u); }

// ---------------- preprocessing ----------------

__global__ __launch_bounds__(256) void k_init(float* deg, int* cnt, int n) {
    int i = blockIdx.x * 256 + threadIdx.x;
    if (i < n) { deg[i] = 2.0f; cnt[i] = 0; }   // self-loop weight 2.0 (improved=True)
}

__global__ __launch_bounds__(256) void k_count(const int* __restrict__ col,
                                               const float* __restrict__ ew,
                                               float* deg, int* cnt, int E) {
    int e = blockIdx.x * 256 + threadIdx.x;
    if (e < E) {
        int c = col[e];
        atomicAdd(&deg[c], ew[e]);
        atomicAdd(&cnt[c], 1);
    }
}

__global__ __launch_bounds__(256) void k_dis(float* deg, int n) {
    int i = blockIdx.x * 256 + threadIdx.x;
    if (i < n) {
        float d = deg[i];
        deg[i] = d > 0.f ? rsqrtf(d) : 0.f;
    }
}

// exclusive prefix scan over cnt -> row_ptr (3-kernel hierarchical scan)
__global__ __launch_bounds__(256) void k_scan1(const int* __restrict__ cnt,
                                               int* __restrict__ row_ptr,
                                               int* __restrict__ bsum, int n) {
    int t = threadIdx.x;
    int base = blockIdx.x * 1024 + t * 4;
    int v0 = (base + 0 < n) ? cnt[base + 0] : 0;
    int v1 = (base + 1 < n) ? cnt[base + 1] : 0;
    int v2 = (base + 2 < n) ? cnt[base + 2] : 0;
    int v3 = (base + 3 < n) ? cnt[base + 3] : 0;
    int tsum = v0 + v1 + v2 + v3;
    int lane = t & 63, wv = t >> 6;
    int val = tsum;
    #pragma unroll
    for (int d = 1; d < 64; d <<= 1) {
        int u = __shfl_up(val, d, 64);
        if (lane >= d) val += u;
    }
    __shared__ int ws[4];
    if (lane == 63) ws[wv] = val;
    __syncthreads();
    int woff = 0;
    #pragma unroll
    for (int i = 0; i < 4; ++i) if (i < wv) woff += ws[i];
    int excl = woff + val - tsum;
    if (base + 0 < n) row_ptr[base + 0] = excl;  excl += v0;
    if (base + 1 < n) row_ptr[base + 1] = excl;  excl += v1;
    if (base + 2 < n) row_ptr[base + 2] = excl;  excl += v2;
    if (base + 3 < n) row_ptr[base + 3] = excl;
    if (t == 255) bsum[blockIdx.x] = woff + val;   // block total
}

__global__ __launch_bounds__(128) void k_scan2(int* bsum, int nb, int* row_ptr, int n, int E) {
    int t = threadIdx.x;
    int v = (t < nb) ? bsum[t] : 0;
    int lane = t & 63, wv = t >> 6;
    int val = v;
    #pragma unroll
    for (int d = 1; d < 64; d <<= 1) {
        int u = __shfl_up(val, d, 64);
        if (lane >= d) val += u;
    }
    __shared__ int ws[2];
    if (lane == 63) ws[wv] = val;
    __syncthreads();
    int woff = (wv == 1) ? ws[0] : 0;
    if (t < nb) bsum[t] = woff + val - v;   // exclusive
    if (t == 0) row_ptr[n] = E;
}

__global__ __launch_bounds__(256) void k_scan3(int* __restrict__ row_ptr,
                                               const int* __restrict__ bsum,
                                               int* __restrict__ cursor, int n) {
    int i = blockIdx.x * 256 + threadIdx.x;
    if (i < n) {
        row_ptr[i] += bsum[i >> 10];
        cursor[i] = 0;
    }
}

__global__ __launch_bounds__(256) void k_fill(const int* __restrict__ rowi,
                                              const int* __restrict__ coli,
                                              const float* __restrict__ ew,
                                              const float* __restrict__ dis,
                                              const int* __restrict__ row_ptr,
                                              int* cursor,
                                              int2* __restrict__ csr, int E) {
    int e = blockIdx.x * 256 + threadIdx.x;
    if (e < E) {
        int c = coli[e], r = rowi[e];
        int pos = row_ptr[c] + atomicAdd(&cursor[c], 1);
        csr[pos] = make_int2(r, __float_as_int(dis[r] * ew[e]));  // dis[c] applied at segment end
    }
}

// ---------------- W prep: Wt[n][k] = bf16(W[k][n]) ----------------

__global__ __launch_bounds__(256) void k_prep_w(const float* __restrict__ W,
                                                short* __restrict__ Wt, int K) {
    int i = blockIdx.x * 256 + threadIdx.x;   // over 128*K
    if (i < 128 * K) {
        int k = i % K, ncol = i / K;
        Wt[i] = f2bf(W[(size_t)k * 128 + ncol]);
    }
}

// ---------------- bf16 MFMA GEMM: C[n,128] = A[n,K] @ B[K,128] ----------------
// Bt pre-transposed bf16 [128][K]. 512 threads = 8 waves, 256 rows/block,
// each wave 32 rows x 128 cols, mfma_f32_16x16x32_bf16. LDS XOR swizzle on Bt.
// ABF: A is bf16 (direct short8 frags) else fp32 with inline cvt.
// OUTBF: C written as bf16 (no bias) else fp32 (+bias).

template<int K, bool ABF, bool OUTBF>
__global__ __launch_bounds__(512) void k_gemm(const void* __restrict__ Av,
                                              const short* __restrict__ Bt,
                                              const float* __restrict__ bias,
                                              void* __restrict__ Cv, int n) {
    __shared__ short Blds[128 * K];
    int t = threadIdx.x;

    const int CHK = K / 8;                    // 16B chunks per row
    for (int c = t; c < 128 * CHK; c += 512) {
        int col = c / CHK;
        int kb  = (c % CHK) * 16;
        int dst = col * (K * 2) + (kb ^ ((col & 7) << 4));
        *(float4*)((char*)Blds + dst) =
            *(const float4*)((const char*)Bt + (size_t)col * (K * 2) + kb);
    }
    __syncthreads();

    int wave = t >> 6, lane = t & 63;
    int lg = lane >> 4, lr = lane & 15;
    long row_base = (long)blockIdx.x * 256 + wave * 32;

    long ra0 = row_base + lr;      if (ra0 > n - 1) ra0 = n - 1;   // clamped, stores guarded
    long ra1 = row_base + 16 + lr; if (ra1 > n - 1) ra1 = n - 1;

    f32x4 acc[2][8];
    #pragma unroll
    for (int i = 0; i < 2; ++i)
        #pragma unroll
        for (int j = 0; j < 8; ++j) acc[i][j] = (f32x4){0.f, 0.f, 0.f, 0.f};

    const float* paf0 = (const float*)Av + ra0 * K + lg * 8;
    const float* paf1 = (const float*)Av + ra1 * K + lg * 8;
    const short* pab0 = (const short*)Av + ra0 * K + lg * 8;
    const short* pab1 = (const short*)Av + ra1 * K + lg * 8;

    for (int k0 = 0; k0 < K; k0 += 32) {
        short8 a0, a1;
        if constexpr (ABF) {
            a0 = *(const short8*)(pab0 + k0);
            a1 = *(const short8*)(pab1 + k0);
        } else {
            float4 x0 = *(const float4*)(paf0 + k0);
            float4 x1 = *(const float4*)(paf0 + k0 + 4);
            float4 y0 = *(const float4*)(paf1 + k0);
            float4 y1 = *(const float4*)(paf1 + k0 + 4);
            a0[0]=f2bf(x0.x); a0[1]=f2bf(x0.y); a0[2]=f2bf(x0.z); a0[3]=f2bf(x0.w);
            a0[4]=f2bf(x1.x); a0[5]=f2bf(x1.y); a0[6]=f2bf(x1.z); a0[7]=f2bf(x1.w);
            a1[0]=f2bf(y0.x); a1[1]=f2bf(y0.y); a1[2]=f2bf(y0.z); a1[3]=f2bf(y0.w);
            a1[4]=f2bf(y1.x); a1[5]=f2bf(y1.y); a1[6]=f2bf(y1.z); a1[7]=f2bf(y1.w);
        }

        int kb = (k0 + lg * 8) * 2;
        #pragma unroll
        for (int cb = 0; cb < 8; ++cb) {
            int col = cb * 16 + lr;
            short8 b = *(short8*)((char*)Blds + col * (K * 2) + (kb ^ ((col & 7) << 4)));
            acc[0][cb] = __builtin_amdgcn_mfma_f32_16x16x32_bf16(a0, b, acc[0][cb], 0, 0, 0);
            acc[1][cb] = __builtin_amdgcn_mfma_f32_16x16x32_bf16(a1, b, acc[1][cb], 0, 0, 0);
        }
    }

    // D: col = lane&15, row = (lane>>4)*4 + reg
    #pragma unroll
    for (int rf = 0; rf < 2; ++rf) {
        #pragma unroll
        for (int cb = 0; cb < 8; ++cb) {
            int col = cb * 16 + lr;
            float bv = (!OUTBF && bias) ? bias[col] : 0.f;
            #pragma unroll
            for (int r = 0; r < 4; ++r) {
                long row = row_base + rf * 16 + lg * 4 + r;
                if (row < n) {
                    if constexpr (OUTBF)
                        ((ushort*)Cv)[row * 128 + col] = f2bfu(acc[rf][cb][r]);
                    else
                        ((float*)Cv)[row * 128 + col] = acc[rf][cb][r] + bv;
                }
            }
        }
    }
}

// ---------------- aggregation: dst[c] = bf16( dis[c]*sum w_e*src[r_e] + 2*dis[c]^2*src[c] (+bias,relu) )
// src/dst bf16 [n][128]; one wave per node, uint (2 bf16) per lane; unroll 4, fp32 accum.

__global__ __launch_bounds__(256) void k_agg(const uint* __restrict__ src,
                                             const int* __restrict__ row_ptr,
                                             const int2* __restrict__ csr,
                                             const float* __restrict__ dis,
                                             const float* __restrict__ bias,
                                             uint* __restrict__ dst,
                                             int n, int do_relu) {
    int wid = (blockIdx.x * 256 + threadIdx.x) >> 6;
    int lane = threadIdx.x & 63;
    if (wid >= n) return;
    int e0 = row_ptr[wid], e1 = row_ptr[wid + 1];

    float x0 = 0.f, y0 = 0.f, x1 = 0.f, y1 = 0.f;
    float x2 = 0.f, y2 = 0.f, x3 = 0.f, y3 = 0.f;
    int e = e0;
    for (; e + 3 < e1; e += 4) {
        int2 c0 = csr[e], c1 = csr[e + 1], c2 = csr[e + 2], c3 = csr[e + 3];
        uint v0 = src[(size_t)c0.x * 64 + lane];
        uint v1 = src[(size_t)c1.x * 64 + lane];
        uint v2 = src[(size_t)c2.x * 64 + lane];
        uint v3 = src[(size_t)c3.x * 64 + lane];
        float w0 = __int_as_float(c0.y), w1 = __int_as_float(c1.y);
        float w2 = __int_as_float(c2.y), w3 = __int_as_float(c3.y);
        x0 += w0 * bfu_lo(v0); y0 += w0 * bfu_hi(v0);
        x1 += w1 * bfu_lo(v1); y1 += w1 * bfu_hi(v1);
        x2 += w2 * bfu_lo(v2); y2 += w2 * bfu_hi(v2);
        x3 += w3 * bfu_lo(v3); y3 += w3 * bfu_hi(v3);
    }
    for (; e < e1; ++e) {
        int2 c = csr[e];
        uint v = src[(size_t)c.x * 64 + lane];
        float w = __int_as_float(c.y);
        x0 += w * bfu_lo(v); y0 += w * bfu_hi(v);
    }
    float dc = dis[wid];
    uint sv = src[(size_t)wid * 64 + lane];
    float sw = 2.f * dc * dc;
    float ox = dc * ((x0 + x1) + (x2 + x3)) + sw * bfu_lo(sv);
    float oy = dc * ((y0 + y1) + (y2 + y3)) + sw * bfu_hi(sv);
    if (bias) { ox += bias[lane * 2]; oy += bias[lane * 2 + 1]; }
    if (do_relu) { ox = fmaxf(ox, 0.f); oy = fmaxf(oy, 0.f); }
    dst[(size_t)wid * 64 + lane] = (uint)f2bfu(ox) | ((uint)f2bfu(oy) << 16);
}

// ---------------- launch ----------------

extern "C" void kernel_launch(void* const* d_in, const int* in_sizes, int n_in,
                              void* d_out, int out_size, void* d_ws, size_t ws_size,
                              hipStream_t stream) {
    const float* x    = (const float*)d_in[0];
    const int*   ei   = (const int*)d_in[1];   // [2,E]: row then col
    const float* ew   = (const float*)d_in[2];
    const float* W1   = (const float*)d_in[3];
    const float* b1   = (const float*)d_in[4];
    const float* Wmu  = (const float*)d_in[5];
    const float* bmu  = (const float*)d_in[6];
    const float* Wvar = (const float*)d_in[7];
    const float* bvar = (const float*)d_in[8];

    const int E = in_sizes[2];          // 1,600,000
    const int N = in_sizes[0] / 256;    // 100,000
    const int* rowi = ei;
    const int* coli = ei + E;

    char* base = (char*)d_ws;
    size_t off = 0;
    auto alloc = [&](size_t bytes) -> void* {
        void* p = base + off;
        off = (off + bytes + 511) & ~(size_t)511;
        return p;
    };
    float* deg     = (float*)alloc((size_t)N * 4);       // becomes dis in place
    int*   cnt     = (int*)  alloc((size_t)N * 4);
    int*   row_ptr = (int*)  alloc((size_t)(N + 1) * 4);
    int*   cursor  = (int*)  alloc((size_t)N * 4);
    int*   bsum    = (int*)  alloc(1024 * 4);
    int2*  csr     = (int2*) alloc((size_t)E * 8);
    uint*  xw      = (uint*) alloc((size_t)N * 64 * 4);  // bf16 [N][128]
    uint*  feat    = (uint*) alloc((size_t)N * 64 * 4);  // bf16 [N][128]
    short* W1t     = (short*)alloc((size_t)256 * 128 * 2);
    short* Wmut    = (short*)alloc((size_t)128 * 128 * 2);
    short* Wvart   = (short*)alloc((size_t)128 * 128 * 2);
    uint*  g       = xw;   // xw dead after pass-1 aggregation

    float* mu  = (float*)d_out;
    float* var = mu + (size_t)N * 128;

    int nb = CDIV(N, 1024);

    k_init  <<<CDIV(N, 256), 256, 0, stream>>>(deg, cnt, N);
    k_count <<<CDIV(E, 256), 256, 0, stream>>>(coli, ew, deg, cnt, E);
    k_dis   <<<CDIV(N, 256), 256, 0, stream>>>(deg, N);
    k_scan1 <<<nb, 256, 0, stream>>>(cnt, row_ptr, bsum, N);
    k_scan2 <<<1, 128, 0, stream>>>(bsum, nb, row_ptr, N, E);
    k_scan3 <<<CDIV(N, 256), 256, 0, stream>>>(row_ptr, bsum, cursor, N);
    k_fill  <<<CDIV(E, 256), 256, 0, stream>>>(rowi, coli, ew, deg, row_ptr, cursor, csr, E);
    k_prep_w<<<CDIV(256 * 128, 256), 256, 0, stream>>>(W1,   W1t,   256);
    k_prep_w<<<CDIV(128 * 128, 256), 256, 0, stream>>>(Wmu,  Wmut,  128);
    k_prep_w<<<CDIV(128 * 128, 256), 256, 0, stream>>>(Wvar, Wvart, 128);

    // layer 1: xw = bf16(x@W1) ; feat = bf16(relu(A·xw + b1))
    k_gemm<256, false, true><<<CDIV(N, 256), 512, 0, stream>>>(x, W1t, nullptr, xw, N);
    k_agg<<<CDIV(N * 64, 256), 256, 0, stream>>>(xw, row_ptr, csr, deg, b1, feat, N, 1);

    // layer 2 (linearity swap): g = bf16(A·feat) ; mu = g@Wmu+bmu ; var = g@Wvar+bvar
    k_agg<<<CDIV(N * 64, 256), 256, 0, stream>>>(feat, row_ptr, csr, deg, nullptr, g, N, 0);
    k_gemm<128, true, false><<<CDIV(N, 256), 512, 0, stream>>>(g, Wmut,  bmu,  mu,  N);
    k_gemm<128, true, false><<<CDIV(N, 256), 512, 0, stream>>>(g, Wvart, bvar, var, N);
}

// Round 4
// 358.951 us; speedup vs baseline: 2.1007x; 1.3157x over previous
//
#include <hip/hip_runtime.h>
#include <hip/hip_bf16.h>

#define CDIV(a,b) (((a)+(b)-1)/(b))

typedef __attribute__((ext_vector_type(8))) short short8;   // 8 bf16 (4 VGPRs)
typedef __attribute__((ext_vector_type(4))) float f32x4;    // MFMA C/D frag

static __device__ inline short f2bf(float f) {
    union { __hip_bfloat16 h; short s; } u;
    u.h = __float2bfloat16(f);
    return u.s;
}
static __device__ inline ushort f2bfu(float f) { return (ushort)f2bf(f); }
static __device__ inline float bfu_lo(uint v) { return __uint_as_float(v << 16); }
static __device__ inline float bfu_hi(uint v) { return __uint_as_float(v & 0xffff0000u); }

// ---------------- preprocessing ----------------
// pack[c]: bits 40..63 = edge count, bits 0..39 = sum(ew) in 2^-24 fixed point.
// One 64-bit atomic per edge; returned old value gives rank within segment.

__global__ __launch_bounds__(256) void k_init(unsigned long long* pack, int n) {
    int i = blockIdx.x * 256 + threadIdx.x;
    if (i < n) pack[i] = 0ull;
}

__global__ __launch_bounds__(256) void k_count(const int* __restrict__ col,
                                               const float* __restrict__ ew,
                                               unsigned long long* pack,
                                               int* __restrict__ rank, int E) {
    int e = blockIdx.x * 256 + threadIdx.x;
    if (e < E) {
        int c = col[e];
        unsigned long long q = (unsigned long long)(ew[e] * 16777216.0f + 0.5f);
        unsigned long long old = atomicAdd(&pack[c], (1ull << 40) | q);
        rank[e] = (int)(old >> 40);
    }
}

// dis = rsqrt(2 + fixsum*2^-24); cnt for scan
__global__ __launch_bounds__(256) void k_dis(const unsigned long long* __restrict__ pack,
                                             float* __restrict__ dis,
                                             int* __restrict__ cnt, int n) {
    int i = blockIdx.x * 256 + threadIdx.x;
    if (i < n) {
        unsigned long long p = pack[i];
        float deg = 2.0f + (float)(p & ((1ull << 40) - 1)) * (1.0f / 16777216.0f);
        dis[i] = rsqrtf(deg);                 // deg >= 2 always
        cnt[i] = (int)(p >> 40);
    }
}

// exclusive prefix scan over cnt -> row_ptr (3-kernel hierarchical scan)
__global__ __launch_bounds__(256) void k_scan1(const int* __restrict__ cnt,
                                               int* __restrict__ row_ptr,
                                               int* __restrict__ bsum, int n) {
    int t = threadIdx.x;
    int base = blockIdx.x * 1024 + t * 4;
    int v0 = (base + 0 < n) ? cnt[base + 0] : 0;
    int v1 = (base + 1 < n) ? cnt[base + 1] : 0;
    int v2 = (base + 2 < n) ? cnt[base + 2] : 0;
    int v3 = (base + 3 < n) ? cnt[base + 3] : 0;
    int tsum = v0 + v1 + v2 + v3;
    int lane = t & 63, wv = t >> 6;
    int val = tsum;
    #pragma unroll
    for (int d = 1; d < 64; d <<= 1) {
        int u = __shfl_up(val, d, 64);
        if (lane >= d) val += u;
    }
    __shared__ int ws[4];
    if (lane == 63) ws[wv] = val;
    __syncthreads();
    int woff = 0;
    #pragma unroll
    for (int i = 0; i < 4; ++i) if (i < wv) woff += ws[i];
    int excl = woff + val - tsum;
    if (base + 0 < n) row_ptr[base + 0] = excl;  excl += v0;
    if (base + 1 < n) row_ptr[base + 1] = excl;  excl += v1;
    if (base + 2 < n) row_ptr[base + 2] = excl;  excl += v2;
    if (base + 3 < n) row_ptr[base + 3] = excl;
    if (t == 255) bsum[blockIdx.x] = woff + val;   // block total
}

__global__ __launch_bounds__(128) void k_scan2(int* bsum, int nb, int* row_ptr, int n, int E) {
    int t = threadIdx.x;
    int v = (t < nb) ? bsum[t] : 0;
    int lane = t & 63, wv = t >> 6;
    int val = v;
    #pragma unroll
    for (int d = 1; d < 64; d <<= 1) {
        int u = __shfl_up(val, d, 64);
        if (lane >= d) val += u;
    }
    __shared__ int ws[2];
    if (lane == 63) ws[wv] = val;
    __syncthreads();
    int woff = (wv == 1) ? ws[0] : 0;
    if (t < nb) bsum[t] = woff + val - v;   // exclusive
    if (t == 0) row_ptr[n] = E;
}

__global__ __launch_bounds__(256) void k_scan3(int* __restrict__ row_ptr,
                                               const int* __restrict__ bsum, int n) {
    int i = blockIdx.x * 256 + threadIdx.x;
    if (i < n) row_ptr[i] += bsum[i >> 10];
}

// atomic-free fill: pos = row_ptr[c] + rank[e]
__global__ __launch_bounds__(256) void k_fill(const int* __restrict__ rowi,
                                              const int* __restrict__ coli,
                                              const float* __restrict__ ew,
                                              const int* __restrict__ rank,
                                              const float* __restrict__ dis,
                                              const int* __restrict__ row_ptr,
                                              int2* __restrict__ csr, int E) {
    int e = blockIdx.x * 256 + threadIdx.x;
    if (e < E) {
        int c = coli[e], r = rowi[e];
        int pos = row_ptr[c] + rank[e];
        csr[pos] = make_int2(r, __float_as_int(dis[r] * ew[e]));  // dis[c] applied at segment end
    }
}

// ---------------- W prep ----------------

__global__ __launch_bounds__(256) void k_prep_w(const float* __restrict__ W,
                                                short* __restrict__ Wt, int K) {
    int i = blockIdx.x * 256 + threadIdx.x;   // over 128*K
    if (i < 128 * K) {
        int k = i % K, ncol = i / K;
        Wt[i] = f2bf(W[(size_t)k * 128 + ncol]);
    }
}

// Wcat_t[256][128]: cols 0..127 from Wmu, 128..255 from Wvar (transposed, bf16)
__global__ __launch_bounds__(256) void k_prep_wcat(const float* __restrict__ Wmu,
                                                   const float* __restrict__ Wvar,
                                                   short* __restrict__ Wt) {
    int i = blockIdx.x * 256 + threadIdx.x;   // over 256*128
    if (i < 256 * 128) {
        int k = i & 127, col = i >> 7;
        float v = (col < 128) ? Wmu[(size_t)k * 128 + col] : Wvar[(size_t)k * 128 + (col - 128)];
        Wt[i] = f2bf(v);
    }
}

// ---------------- bf16 MFMA GEMM 1: C[n,128] = bf16( A[n,256](fp32) @ B ) ----------------
// 512 threads = 8 waves, 256 rows/block, wave = 32 rows x 128 cols. LDS XOR swizzle.

template<int K>
__global__ __launch_bounds__(512) void k_gemm1(const float* __restrict__ A,
                                               const short* __restrict__ Bt,
                                               uint* __restrict__ C, int n) {
    __shared__ short Blds[128 * K];
    int t = threadIdx.x;

    const int CHK = K / 8;
    for (int c = t; c < 128 * CHK; c += 512) {
        int col = c / CHK;
        int kb  = (c % CHK) * 16;
        int dst = col * (K * 2) + (kb ^ ((col & 7) << 4));
        *(float4*)((char*)Blds + dst) =
            *(const float4*)((const char*)Bt + (size_t)col * (K * 2) + kb);
    }
    __syncthreads();

    int wave = t >> 6, lane = t & 63;
    int lg = lane >> 4, lr = lane & 15;
    long row_base = (long)blockIdx.x * 256 + wave * 32;

    long ra0 = row_base + lr;      if (ra0 > n - 1) ra0 = n - 1;
    long ra1 = row_base + 16 + lr; if (ra1 > n - 1) ra1 = n - 1;

    f32x4 acc[2][8];
    #pragma unroll
    for (int i = 0; i < 2; ++i)
        #pragma unroll
        for (int j = 0; j < 8; ++j) acc[i][j] = (f32x4){0.f, 0.f, 0.f, 0.f};

    const float* pa0 = A + ra0 * K + lg * 8;
    const float* pa1 = A + ra1 * K + lg * 8;

    for (int k0 = 0; k0 < K; k0 += 32) {
        float4 x0 = *(const float4*)(pa0 + k0);
        float4 x1 = *(const float4*)(pa0 + k0 + 4);
        float4 y0 = *(const float4*)(pa1 + k0);
        float4 y1 = *(const float4*)(pa1 + k0 + 4);
        short8 a0, a1;
        a0[0]=f2bf(x0.x); a0[1]=f2bf(x0.y); a0[2]=f2bf(x0.z); a0[3]=f2bf(x0.w);
        a0[4]=f2bf(x1.x); a0[5]=f2bf(x1.y); a0[6]=f2bf(x1.z); a0[7]=f2bf(x1.w);
        a1[0]=f2bf(y0.x); a1[1]=f2bf(y0.y); a1[2]=f2bf(y0.z); a1[3]=f2bf(y0.w);
        a1[4]=f2bf(y1.x); a1[5]=f2bf(y1.y); a1[6]=f2bf(y1.z); a1[7]=f2bf(y1.w);

        int kb = (k0 + lg * 8) * 2;
        #pragma unroll
        for (int cb = 0; cb < 8; ++cb) {
            int col = cb * 16 + lr;
            short8 b = *(short8*)((char*)Blds + col * (K * 2) + (kb ^ ((col & 7) << 4)));
            acc[0][cb] = __builtin_amdgcn_mfma_f32_16x16x32_bf16(a0, b, acc[0][cb], 0, 0, 0);
            acc[1][cb] = __builtin_amdgcn_mfma_f32_16x16x32_bf16(a1, b, acc[1][cb], 0, 0, 0);
        }
    }

    #pragma unroll
    for (int rf = 0; rf < 2; ++rf) {
        #pragma unroll
        for (int cb = 0; cb < 8; ++cb) {
            int col = cb * 16 + lr;
            #pragma unroll
            for (int r = 0; r < 4; ++r) {
                long row = row_base + rf * 16 + lg * 4 + r;
                if (row < n) ((ushort*)C)[row * 128 + col] = f2bfu(acc[rf][cb][r]);
            }
        }
    }
}

// ---------------- fused mu/var GEMM: [mu|var] = A[n,128](bf16) @ Wcat[128,256] + [bmu|bvar] ----------------
// 512 threads = 8 waves, 128 rows x 256 cols per block; wave w: rows (w>>1)*32, cols (w&1)*128.

__global__ __launch_bounds__(512) void k_gemm2(const short* __restrict__ A,
                                               const short* __restrict__ Bt,   // [256][128]
                                               const float* __restrict__ bmu,
                                               const float* __restrict__ bvar,
                                               float* __restrict__ out,        // mu at 0, var at n*128
                                               int n) {
    const int K = 128;
    __shared__ short Blds[256 * K];
    int t = threadIdx.x;

    const int CHK = K / 8;   // 16
    for (int c = t; c < 256 * CHK; c += 512) {
        int col = c / CHK;
        int kb  = (c % CHK) * 16;
        int dst = col * (K * 2) + (kb ^ ((col & 7) << 4));
        *(float4*)((char*)Blds + dst) =
            *(const float4*)((const char*)Bt + (size_t)col * (K * 2) + kb);
    }
    __syncthreads();

    int wave = t >> 6, lane = t & 63;
    int lg = lane >> 4, lr = lane & 15;
    int colbase = (wave & 1) * 128;
    long row_base = (long)blockIdx.x * 128 + (wave >> 1) * 32;

    long ra0 = row_base + lr;      if (ra0 > n - 1) ra0 = n - 1;
    long ra1 = row_base + 16 + lr; if (ra1 > n - 1) ra1 = n - 1;

    f32x4 acc[2][8];
    #pragma unroll
    for (int i = 0; i < 2; ++i)
        #pragma unroll
        for (int j = 0; j < 8; ++j) acc[i][j] = (f32x4){0.f, 0.f, 0.f, 0.f};

    const short* pa0 = A + ra0 * K + lg * 8;
    const short* pa1 = A + ra1 * K + lg * 8;

    #pragma unroll
    for (int k0 = 0; k0 < K; k0 += 32) {
        short8 a0 = *(const short8*)(pa0 + k0);
        short8 a1 = *(const short8*)(pa1 + k0);
        int kb = (k0 + lg * 8) * 2;
        #pragma unroll
        for (int cb = 0; cb < 8; ++cb) {
            int col = colbase + cb * 16 + lr;
            short8 b = *(short8*)((char*)Blds + col * (K * 2) + (kb ^ ((col & 7) << 4)));
            acc[0][cb] = __builtin_amdgcn_mfma_f32_16x16x32_bf16(a0, b, acc[0][cb], 0, 0, 0);
            acc[1][cb] = __builtin_amdgcn_mfma_f32_16x16x32_bf16(a1, b, acc[1][cb], 0, 0, 0);
        }
    }

    #pragma unroll
    for (int rf = 0; rf < 2; ++rf) {
        #pragma unroll
        for (int cb = 0; cb < 8; ++cb) {
            int colc = colbase + cb * 16 + lr;
            bool is_var = colc >= 128;
            int col = is_var ? colc - 128 : colc;
            float bv = is_var ? bvar[col] : bmu[col];
            size_t obase = is_var ? (size_t)n * 128 : 0;
            #pragma unroll
            for (int r = 0; r < 4; ++r) {
                long row = row_base + rf * 16 + lg * 4 + r;
                if (row < n) out[obase + (size_t)row * 128 + col] = acc[rf][cb][r] + bv;
            }
        }
    }
}

// ---------------- aggregation: dst[c] = bf16( dis[c]*sum w_e*src[r_e] + 2*dis[c]^2*src[c] (+bias,relu) )

__global__ __launch_bounds__(256) void k_agg(const uint* __restrict__ src,
                                             const int* __restrict__ row_ptr,
                                             const int2* __restrict__ csr,
                                             const float* __restrict__ dis,
                                             const float* __restrict__ bias,
                                             uint* __restrict__ dst,
                                             int n, int do_relu) {
    int wid = (blockIdx.x * 256 + threadIdx.x) >> 6;
    int lane = threadIdx.x & 63;
    if (wid >= n) return;
    int e0 = row_ptr[wid], e1 = row_ptr[wid + 1];

    float x0 = 0.f, y0 = 0.f, x1 = 0.f, y1 = 0.f;
    float x2 = 0.f, y2 = 0.f, x3 = 0.f, y3 = 0.f;
    int e = e0;
    for (; e + 3 < e1; e += 4) {
        int2 c0 = csr[e], c1 = csr[e + 1], c2 = csr[e + 2], c3 = csr[e + 3];
        uint v0 = src[(size_t)c0.x * 64 + lane];
        uint v1 = src[(size_t)c1.x * 64 + lane];
        uint v2 = src[(size_t)c2.x * 64 + lane];
        uint v3 = src[(size_t)c3.x * 64 + lane];
        float w0 = __int_as_float(c0.y), w1 = __int_as_float(c1.y);
        float w2 = __int_as_float(c2.y), w3 = __int_as_float(c3.y);
        x0 += w0 * bfu_lo(v0); y0 += w0 * bfu_hi(v0);
        x1 += w1 * bfu_lo(v1); y1 += w1 * bfu_hi(v1);
        x2 += w2 * bfu_lo(v2); y2 += w2 * bfu_hi(v2);
        x3 += w3 * bfu_lo(v3); y3 += w3 * bfu_hi(v3);
    }
    for (; e < e1; ++e) {
        int2 c = csr[e];
        uint v = src[(size_t)c.x * 64 + lane];
        float w = __int_as_float(c.y);
        x0 += w * bfu_lo(v); y0 += w * bfu_hi(v);
    }
    float dc = dis[wid];
    uint sv = src[(size_t)wid * 64 + lane];
    float sw = 2.f * dc * dc;
    float ox = dc * ((x0 + x1) + (x2 + x3)) + sw * bfu_lo(sv);
    float oy = dc * ((y0 + y1) + (y2 + y3)) + sw * bfu_hi(sv);
    if (bias) { ox += bias[lane * 2]; oy += bias[lane * 2 + 1]; }
    if (do_relu) { ox = fmaxf(ox, 0.f); oy = fmaxf(oy, 0.f); }
    dst[(size_t)wid * 64 + lane] = (uint)f2bfu(ox) | ((uint)f2bfu(oy) << 16);
}

// ---------------- launch ----------------

extern "C" void kernel_launch(void* const* d_in, const int* in_sizes, int n_in,
                              void* d_out, int out_size, void* d_ws, size_t ws_size,
                              hipStream_t stream) {
    const float* x    = (const float*)d_in[0];
    const int*   ei   = (const int*)d_in[1];   // [2,E]: row then col
    const float* ew   = (const float*)d_in[2];
    const float* W1   = (const float*)d_in[3];
    const float* b1   = (const float*)d_in[4];
    const float* Wmu  = (const float*)d_in[5];
    const float* bmu  = (const float*)d_in[6];
    const float* Wvar = (const float*)d_in[7];
    const float* bvar = (const float*)d_in[8];

    const int E = in_sizes[2];          // 1,600,000
    const int N = in_sizes[0] / 256;    // 100,000
    const int* rowi = ei;
    const int* coli = ei + E;

    char* base = (char*)d_ws;
    size_t off = 0;
    auto alloc = [&](size_t bytes) -> void* {
        void* p = base + off;
        off = (off + bytes + 511) & ~(size_t)511;
        return p;
    };
    unsigned long long* pack = (unsigned long long*)alloc((size_t)N * 8);
    float* dis     = (float*)alloc((size_t)N * 4);
    int*   cnt     = (int*)  alloc((size_t)N * 4);
    int*   row_ptr = (int*)  alloc((size_t)(N + 1) * 4);
    int*   rank    = (int*)  alloc((size_t)E * 4);
    int*   bsum    = (int*)  alloc(1024 * 4);
    int2*  csr     = (int2*) alloc((size_t)E * 8);
    uint*  xw      = (uint*) alloc((size_t)N * 64 * 4);  // bf16 [N][128]
    uint*  feat    = (uint*) alloc((size_t)N * 64 * 4);  // bf16 [N][128]
    short* W1t     = (short*)alloc((size_t)256 * 128 * 2);
    short* Wcat    = (short*)alloc((size_t)256 * 128 * 2);
    uint*  g       = xw;   // xw dead after pass-1 aggregation

    int nb = CDIV(N, 1024);

    k_init  <<<CDIV(N, 256), 256, 0, stream>>>(pack, N);
    k_count <<<CDIV(E, 256), 256, 0, stream>>>(coli, ew, pack, rank, E);
    k_dis   <<<CDIV(N, 256), 256, 0, stream>>>(pack, dis, cnt, N);
    k_scan1 <<<nb, 256, 0, stream>>>(cnt, row_ptr, bsum, N);
    k_scan2 <<<1, 128, 0, stream>>>(bsum, nb, row_ptr, N, E);
    k_scan3 <<<CDIV(N, 256), 256, 0, stream>>>(row_ptr, bsum, N);
    k_fill  <<<CDIV(E, 256), 256, 0, stream>>>(rowi, coli, ew, rank, dis, row_ptr, csr, E);
    k_prep_w   <<<CDIV(256 * 128, 256), 256, 0, stream>>>(W1, W1t, 256);
    k_prep_wcat<<<CDIV(256 * 128, 256), 256, 0, stream>>>(Wmu, Wvar, Wcat);

    // layer 1: xw = bf16(x@W1) ; feat = bf16(relu(A·xw + b1))
    k_gemm1<256><<<CDIV(N, 256), 512, 0, stream>>>(x, W1t, xw, N);
    k_agg<<<CDIV(N * 64, 256), 256, 0, stream>>>(xw, row_ptr, csr, dis, b1, feat, N, 1);

    // layer 2 (linearity swap): g = bf16(A·feat) ; [mu|var] = g@[Wmu|Wvar] + [bmu|bvar]
    k_agg<<<CDIV(N * 64, 256), 256, 0, stream>>>(feat, row_ptr, csr, dis, nullptr, g, N, 0);
    k_gemm2<<<CDIV(N, 128), 512, 0, stream>>>((const short*)g, Wcat, bmu, bvar, (float*)d_out, N);
}

// Round 6
// 305.688 us; speedup vs baseline: 2.4667x; 1.1742x over previous
//
#include <hip/hip_runtime.h>
#include <hip/hip_bf16.h>

#define CDIV(a,b) (((a)+(b)-1)/(b))

typedef __attribute__((ext_vector_type(8))) short short8;   // 8 bf16 (4 VGPRs)
typedef __attribute__((ext_vector_type(4))) float f32x4;    // MFMA C/D frag

static __device__ inline short f2bf(float f) {
    union { __hip_bfloat16 h; short s; } u;
    u.h = __float2bfloat16(f);
    return u.s;
}
static __device__ inline ushort f2bfu(float f) { return (ushort)f2bf(f); }
static __device__ inline float bfu_lo(uint v) { return __uint_as_float(v << 16); }
static __device__ inline float bfu_hi(uint v) { return __uint_as_float(v & 0xffff0000u); }

// ---------------- init + weight prep (independent work, one launch) ----------------
// pack[c]: bits 40..63 = edge count, bits 0..39 = sum(ew) in 2^-24 fixed point.

__global__ __launch_bounds__(512) void k_init(unsigned long long* __restrict__ pack, int n,
                                              const float* __restrict__ W1,
                                              short* __restrict__ W1t,
                                              const float* __restrict__ Wmu,
                                              const float* __restrict__ Wvar,
                                              short* __restrict__ Wcat) {
    int i = blockIdx.x * 512 + threadIdx.x;
    if (i < n) pack[i] = 0ull;
    if (i < 128 * 256) {                       // W1t[col][k] = bf16(W1[k][col]), K=256
        int k = i % 256, col = i / 256;
        W1t[i] = f2bf(W1[(size_t)k * 128 + col]);
    } else if (i < 2 * 128 * 256) {            // Wcat[col][k], K=128: col<128 Wmu, else Wvar
        int j = i - 128 * 256;
        int k = j & 127, col = j >> 7;
        float v = (col < 128) ? Wmu[(size_t)k * 128 + col] : Wvar[(size_t)k * 128 + (col - 128)];
        Wcat[j] = f2bf(v);
    }
}

// ---------------- fat kernel: GEMM1 (blocks < nGB) || edge count (blocks >= nGB) ----------------
// GEMM1: xw[n,128] = bf16( x[n,256] @ W1 ). 512 thr = 8 waves, 256 rows/block, LDS XOR swizzle.
// COUNT: one packed 64-bit atomic per edge; old>>40 = rank within segment.

__global__ __launch_bounds__(512) void k_fat(const float* __restrict__ A,
                                             const short* __restrict__ Bt,
                                             ushort* __restrict__ C, int n, int nGB,
                                             const int* __restrict__ col,
                                             const float* __restrict__ ew,
                                             unsigned long long* __restrict__ pack,
                                             int* __restrict__ rank, int E) {
    const int K = 256;
    __shared__ short Blds[128 * K];
    int t = threadIdx.x;

    if (blockIdx.x >= nGB) {                   // ---- count path ----
        int e = (blockIdx.x - nGB) * 512 + t;
        if (e < E) {
            int c = col[e];
            unsigned long long q = (unsigned long long)(ew[e] * 16777216.0f + 0.5f);
            unsigned long long old = atomicAdd(&pack[c], (1ull << 40) | q);
            rank[e] = (int)(old >> 40);
        }
        return;
    }

    // ---- GEMM1 path ----
    const int CHK = K / 8;
    for (int c = t; c < 128 * CHK; c += 512) {
        int colw = c / CHK;
        int kb  = (c % CHK) * 16;
        int dst = colw * (K * 2) + (kb ^ ((colw & 7) << 4));
        *(float4*)((char*)Blds + dst) =
            *(const float4*)((const char*)Bt + (size_t)colw * (K * 2) + kb);
    }
    __syncthreads();

    int wave = t >> 6, lane = t & 63;
    int lg = lane >> 4, lr = lane & 15;
    long row_base = (long)blockIdx.x * 256 + wave * 32;

    long ra0 = row_base + lr;      if (ra0 > n - 1) ra0 = n - 1;   // clamped, stores guarded
    long ra1 = row_base + 16 + lr; if (ra1 > n - 1) ra1 = n - 1;

    f32x4 acc[2][8];
    #pragma unroll
    for (int i = 0; i < 2; ++i)
        #pragma unroll
        for (int j = 0; j < 8; ++j) acc[i][j] = (f32x4){0.f, 0.f, 0.f, 0.f};

    const float* pa0 = A + ra0 * K + lg * 8;
    const float* pa1 = A + ra1 * K + lg * 8;

    for (int k0 = 0; k0 < K; k0 += 32) {
        float4 x0 = *(const float4*)(pa0 + k0);
        float4 x1 = *(const float4*)(pa0 + k0 + 4);
        float4 y0 = *(const float4*)(pa1 + k0);
        float4 y1 = *(const float4*)(pa1 + k0 + 4);
        short8 a0, a1;
        a0[0]=f2bf(x0.x); a0[1]=f2bf(x0.y); a0[2]=f2bf(x0.z); a0[3]=f2bf(x0.w);
        a0[4]=f2bf(x1.x); a0[5]=f2bf(x1.y); a0[6]=f2bf(x1.z); a0[7]=f2bf(x1.w);
        a1[0]=f2bf(y0.x); a1[1]=f2bf(y0.y); a1[2]=f2bf(y0.z); a1[3]=f2bf(y0.w);
        a1[4]=f2bf(y1.x); a1[5]=f2bf(y1.y); a1[6]=f2bf(y1.z); a1[7]=f2bf(y1.w);

        int kb = (k0 + lg * 8) * 2;
        #pragma unroll
        for (int cb = 0; cb < 8; ++cb) {
            int colm = cb * 16 + lr;
            short8 b = *(short8*)((char*)Blds + colm * (K * 2) + (kb ^ ((colm & 7) << 4)));
            acc[0][cb] = __builtin_amdgcn_mfma_f32_16x16x32_bf16(a0, b, acc[0][cb], 0, 0, 0);
            acc[1][cb] = __builtin_amdgcn_mfma_f32_16x16x32_bf16(a1, b, acc[1][cb], 0, 0, 0);
        }
    }

    #pragma unroll
    for (int rf = 0; rf < 2; ++rf) {
        #pragma unroll
        for (int cb = 0; cb < 8; ++cb) {
            int colm = cb * 16 + lr;
            #pragma unroll
            for (int r = 0; r < 4; ++r) {
                long row = row_base + rf * 16 + lg * 4 + r;
                if (row < n) C[row * 128 + colm] = f2bfu(acc[rf][cb][r]);
            }
        }
    }
}

// ---------------- scan1 + dis (fused): reads pack, writes dis, row_ptr partials, bsum ----------------

__global__ __launch_bounds__(256) void k_scan1(const unsigned long long* __restrict__ pack,
                                               float* __restrict__ dis,
                                               int* __restrict__ row_ptr,
                                               int* __restrict__ bsum, int n) {
    int t = threadIdx.x;
    int base = blockIdx.x * 1024 + t * 4;
    int v0 = 0, v1 = 0, v2 = 0, v3 = 0;
    #pragma unroll
    for (int j = 0; j < 4; ++j) {
        int idx = base + j;
        if (idx < n) {
            unsigned long long p = pack[idx];
            float deg = 2.0f + (float)(p & ((1ull << 40) - 1)) * (1.0f / 16777216.0f);
            dis[idx] = rsqrtf(deg);
            int c = (int)(p >> 40);
            if (j == 0) v0 = c; else if (j == 1) v1 = c; else if (j == 2) v2 = c; else v3 = c;
        }
    }
    int tsum = v0 + v1 + v2 + v3;
    int lane = t & 63, wv = t >> 6;
    int val = tsum;
    #pragma unroll
    for (int d = 1; d < 64; d <<= 1) {
        int u = __shfl_up(val, d, 64);
        if (lane >= d) val += u;
    }
    __shared__ int ws[4];
    if (lane == 63) ws[wv] = val;
    __syncthreads();
    int woff = 0;
    #pragma unroll
    for (int i = 0; i < 4; ++i) if (i < wv) woff += ws[i];
    int excl = woff + val - tsum;
    if (base + 0 < n) row_ptr[base + 0] = excl;  excl += v0;
    if (base + 1 < n) row_ptr[base + 1] = excl;  excl += v1;
    if (base + 2 < n) row_ptr[base + 2] = excl;  excl += v2;
    if (base + 3 < n) row_ptr[base + 3] = excl;
    if (t == 255) bsum[blockIdx.x] = woff + val;
}

__global__ __launch_bounds__(128) void k_scan2(int* bsum, int nb, int* row_ptr, int n, int E) {
    int t = threadIdx.x;
    int v = (t < nb) ? bsum[t] : 0;
    int lane = t & 63, wv = t >> 6;
    int val = v;
    #pragma unroll
    for (int d = 1; d < 64; d <<= 1) {
        int u = __shfl_up(val, d, 64);
        if (lane >= d) val += u;
    }
    __shared__ int ws[2];
    if (lane == 63) ws[wv] = val;
    __syncthreads();
    int woff = (wv == 1) ? ws[0] : 0;
    if (t < nb) bsum[t] = woff + val - v;
    if (t == 0) row_ptr[n] = E;
}

__global__ __launch_bounds__(256) void k_scan3(int* __restrict__ row_ptr,
                                               const int* __restrict__ bsum, int n) {
    int i = blockIdx.x * 256 + threadIdx.x;
    if (i < n) row_ptr[i] += bsum[i >> 10];
}

// atomic-free fill: pos = row_ptr[c] + rank[e]
__global__ __launch_bounds__(512) void k_fill(const int* __restrict__ rowi,
                                              const int* __restrict__ coli,
                                              const float* __restrict__ ew,
                                              const int* __restrict__ rank,
                                              const float* __restrict__ dis,
                                              const int* __restrict__ row_ptr,
                                              int2* __restrict__ csr, int E) {
    int e = blockIdx.x * 512 + threadIdx.x;
    if (e < E) {
        int c = coli[e], r = rowi[e];
        int pos = row_ptr[c] + rank[e];
        csr[pos] = make_int2(r, __float_as_int(dis[r] * ew[e]));  // dis[c] applied at segment end
    }
}

// ---------------- aggregation: dst[c] = bf16( dis[c]*sum w_e*src[r_e] + 2*dis[c]^2*src[c] (+bias,relu) )
// src/dst bf16 [n][128]; one wave per node, uint (2 bf16) per lane; unroll 8+2, fp32 accum.
// OUTMODE 0: +bias +relu (pass 1). OUTMODE 1: plain (pass 2).

template<int OUTMODE>
__global__ __launch_bounds__(256) void k_agg(const uint* __restrict__ src,
                                             const int* __restrict__ row_ptr,
                                             const int2* __restrict__ csr,
                                             const float* __restrict__ dis,
                                             const float* __restrict__ bias,
                                             uint* __restrict__ dst, int n) {
    int wid = (blockIdx.x * 256 + threadIdx.x) >> 6;
    int lane = threadIdx.x & 63;
    if (wid >= n) return;
    int e0 = row_ptr[wid], e1 = row_ptr[wid + 1];

    float a0=0.f,b0=0.f,a1=0.f,b1=0.f,a2=0.f,b2=0.f,a3=0.f,b3=0.f;
    float a4=0.f,b4=0.f,a5=0.f,b5=0.f,a6=0.f,b6=0.f,a7=0.f,b7=0.f;
    int e = e0;
    for (; e + 7 < e1; e += 8) {
        int2 c0 = csr[e],     c1 = csr[e + 1], c2 = csr[e + 2], c3 = csr[e + 3];
        int2 c4 = csr[e + 4], c5 = csr[e + 5], c6 = csr[e + 6], c7 = csr[e + 7];
        uint v0 = src[(size_t)c0.x * 64 + lane];
        uint v1 = src[(size_t)c1.x * 64 + lane];
        uint v2 = src[(size_t)c2.x * 64 + lane];
        uint v3 = src[(size_t)c3.x * 64 + lane];
        uint v4 = src[(size_t)c4.x * 64 + lane];
        uint v5 = src[(size_t)c5.x * 64 + lane];
        uint v6 = src[(size_t)c6.x * 64 + lane];
        uint v7 = src[(size_t)c7.x * 64 + lane];
        float w0 = __int_as_float(c0.y), w1 = __int_as_float(c1.y);
        float w2 = __int_as_float(c2.y), w3 = __int_as_float(c3.y);
        float w4 = __int_as_float(c4.y), w5 = __int_as_float(c5.y);
        float w6 = __int_as_float(c6.y), w7 = __int_as_float(c7.y);
        a0 += w0 * bfu_lo(v0); b0 += w0 * bfu_hi(v0);
        a1 += w1 * bfu_lo(v1); b1 += w1 * bfu_hi(v1);
        a2 += w2 * bfu_lo(v2); b2 += w2 * bfu_hi(v2);
        a3 += w3 * bfu_lo(v3); b3 += w3 * bfu_hi(v3);
        a4 += w4 * bfu_lo(v4); b4 += w4 * bfu_hi(v4);
        a5 += w5 * bfu_lo(v5); b5 += w5 * bfu_hi(v5);
        a6 += w6 * bfu_lo(v6); b6 += w6 * bfu_hi(v6);
        a7 += w7 * bfu_lo(v7); b7 += w7 * bfu_hi(v7);
    }
    for (; e + 1 < e1; e += 2) {
        int2 c0 = csr[e], c1 = csr[e + 1];
        uint v0 = src[(size_t)c0.x * 64 + lane];
        uint v1 = src[(size_t)c1.x * 64 + lane];
        float w0 = __int_as_float(c0.y), w1 = __int_as_float(c1.y);
        a0 += w0 * bfu_lo(v0); b0 += w0 * bfu_hi(v0);
        a1 += w1 * bfu_lo(v1); b1 += w1 * bfu_hi(v1);
    }
    if (e < e1) {
        int2 c = csr[e];
        uint v = src[(size_t)c.x * 64 + lane];
        float w = __int_as_float(c.y);
        a0 += w * bfu_lo(v); b0 += w * bfu_hi(v);
    }
    float dc = dis[wid];
    uint sv = src[(size_t)wid * 64 + lane];
    float sw = 2.f * dc * dc;
    float ox = dc * (((a0 + a1) + (a2 + a3)) + ((a4 + a5) + (a6 + a7))) + sw * bfu_lo(sv);
    float oy = dc * (((b0 + b1) + (b2 + b3)) + ((b4 + b5) + (b6 + b7))) + sw * bfu_hi(sv);
    if constexpr (OUTMODE == 0) {
        ox += bias[lane * 2]; oy += bias[lane * 2 + 1];
        ox = fmaxf(ox, 0.f);  oy = fmaxf(oy, 0.f);
    }
    dst[(size_t)wid * 64 + lane] = (uint)f2bfu(ox) | ((uint)f2bfu(oy) << 16);
}

// ---------------- fused mu/var GEMM: [mu|var] = g[n,128](bf16) @ Wcat[128,256] + [bmu|bvar] ----------------

__global__ __launch_bounds__(512) void k_gemm2(const short* __restrict__ A,
                                               const short* __restrict__ Bt,   // [256][128]
                                               const float* __restrict__ bmu,
                                               const float* __restrict__ bvar,
                                               float* __restrict__ out,        // mu at 0, var at n*128
                                               int n) {
    const int K = 128;
    __shared__ short Blds[256 * K];
    int t = threadIdx.x;

    const int CHK = K / 8;   // 16
    for (int c = t; c < 256 * CHK; c += 512) {
        int col = c / CHK;
        int kb  = (c % CHK) * 16;
        int dst = col * (K * 2) + (kb ^ ((col & 7) << 4));
        *(float4*)((char*)Blds + dst) =
            *(const float4*)((const char*)Bt + (size_t)col * (K * 2) + kb);
    }
    __syncthreads();

    int wave = t >> 6, lane = t & 63;
    int lg = lane >> 4, lr = lane & 15;
    int colbase = (wave & 1) * 128;
    long row_base = (long)blockIdx.x * 128 + (wave >> 1) * 32;

    long ra0 = row_base + lr;      if (ra0 > n - 1) ra0 = n - 1;
    long ra1 = row_base + 16 + lr; if (ra1 > n - 1) ra1 = n - 1;

    f32x4 acc[2][8];
    #pragma unroll
    for (int i = 0; i < 2; ++i)
        #pragma unroll
        for (int j = 0; j < 8; ++j) acc[i][j] = (f32x4){0.f, 0.f, 0.f, 0.f};

    const short* pa0 = A + ra0 * K + lg * 8;
    const short* pa1 = A + ra1 * K + lg * 8;

    #pragma unroll
    for (int k0 = 0; k0 < K; k0 += 32) {
        short8 a0 = *(const short8*)(pa0 + k0);
        short8 a1 = *(const short8*)(pa1 + k0);
        int kb = (k0 + lg * 8) * 2;
        #pragma unroll
        for (int cb = 0; cb < 8; ++cb) {
            int col = colbase + cb * 16 + lr;
            short8 b = *(short8*)((char*)Blds + col * (K * 2) + (kb ^ ((col & 7) << 4)));
            acc[0][cb] = __builtin_amdgcn_mfma_f32_16x16x32_bf16(a0, b, acc[0][cb], 0, 0, 0);
            acc[1][cb] = __builtin_amdgcn_mfma_f32_16x16x32_bf16(a1, b, acc[1][cb], 0, 0, 0);
        }
    }

    #pragma unroll
    for (int rf = 0; rf < 2; ++rf) {
        #pragma unroll
        for (int cb = 0; cb < 8; ++cb) {
            int colc = colbase + cb * 16 + lr;
            bool is_var = colc >= 128;
            int col = is_var ? colc - 128 : colc;
            float bv = is_var ? bvar[col] : bmu[col];
            size_t obase = is_var ? (size_t)n * 128 : 0;
            #pragma unroll
            for (int r = 0; r < 4; ++r) {
                long row = row_base + rf * 16 + lg * 4 + r;
                if (row < n)
                    __builtin_nontemporal_store(acc[rf][cb][r] + bv,
                                                &out[obase + (size_t)row * 128 + col]);
            }
        }
    }
}

// ---------------- launch ----------------

extern "C" void kernel_launch(void* const* d_in, const int* in_sizes, int n_in,
                              void* d_out, int out_size, void* d_ws, size_t ws_size,
                              hipStream_t stream) {
    const float* x    = (const float*)d_in[0];
    const int*   ei   = (const int*)d_in[1];   // [2,E]: row then col
    const float* ew   = (const float*)d_in[2];
    const float* W1   = (const float*)d_in[3];
    const float* b1   = (const float*)d_in[4];
    const float* Wmu  = (const float*)d_in[5];
    const float* bmu  = (const float*)d_in[6];
    const float* Wvar = (const float*)d_in[7];
    const float* bvar = (const float*)d_in[8];

    const int E = in_sizes[2];          // 1,600,000
    const int N = in_sizes[0] / 256;    // 100,000
    const int* rowi = ei;
    const int* coli = ei + E;

    char* base = (char*)d_ws;
    size_t off = 0;
    auto alloc = [&](size_t bytes) -> void* {
        void* p = base + off;
        off = (off + bytes + 511) & ~(size_t)511;
        return p;
    };
    unsigned long long* pack = (unsigned long long*)alloc((size_t)N * 8);
    float* dis     = (float*)alloc((size_t)N * 4);
    int*   row_ptr = (int*)  alloc((size_t)(N + 1) * 4);
    int*   rank    = (int*)  alloc((size_t)E * 4);
    int*   bsum    = (int*)  alloc(1024 * 4);
    int2*  csr     = (int2*) alloc((size_t)E * 8);
    uint*  xw      = (uint*) alloc((size_t)N * 64 * 4);  // bf16 [N][128]
    uint*  feat    = (uint*) alloc((size_t)N * 64 * 4);  // bf16 [N][128]
    short* W1t     = (short*)alloc((size_t)256 * 128 * 2);
    short* Wcat    = (short*)alloc((size_t)256 * 128 * 2);
    uint*  g       = xw;   // xw dead after pass-1 aggregation

    int nb   = CDIV(N, 1024);
    int nGB  = CDIV(N, 256);            // 391 gemm blocks
    int nCB  = CDIV(E, 512);            // 3125 count blocks

    // init pack + prep all weights (one launch, independent work)
    k_init<<<CDIV(N, 512), 512, 0, stream>>>(pack, N, W1, W1t, Wmu, Wvar, Wcat);

    // GEMM1 || edge-count in one fat kernel (independent, different bottlenecks)
    k_fat<<<nGB + nCB, 512, 0, stream>>>(x, W1t, (ushort*)xw, N, nGB, coli, ew, pack, rank, E);

    k_scan1<<<nb, 256, 0, stream>>>(pack, dis, row_ptr, bsum, N);
    k_scan2<<<1, 128, 0, stream>>>(bsum, nb, row_ptr, N, E);
    k_scan3<<<CDIV(N, 256), 256, 0, stream>>>(row_ptr, bsum, N);
    k_fill <<<CDIV(E, 512), 512, 0, stream>>>(rowi, coli, ew, rank, dis, row_ptr, csr, E);

    // feat = bf16(relu(A·xw + b1)) ; g = bf16(A·feat) ; [mu|var] = g@[Wmu|Wvar]+[bmu|bvar]
    k_agg<0><<<CDIV(N * 64, 256), 256, 0, stream>>>(xw, row_ptr, csr, dis, b1, feat, N);
    k_agg<1><<<CDIV(N * 64, 256), 256, 0, stream>>>(feat, row_ptr, csr, dis, nullptr, g, N);
    k_gemm2<<<CDIV(N, 128), 512, 0, stream>>>((const short*)g, Wcat, bmu, bvar, (float*)d_out, N);
}